// Round 1
// baseline (10098.199 us; speedup 1.0000x reference)
//
#include <hip/hip_runtime.h>
#include <hip/hip_bf16.h>
#include <math.h>

// Problem constants
#define BB 32     // batch
#define TT 128    // encoder timesteps
#define HH 512    // hidden
#define VV 32000  // vocab
#define SS 64     // decode steps (BLOCK)
#define NSL 8     // slices (blocks) per batch element

__device__ __forceinline__ float tanh_fast(float x) {
    return 1.f - 2.f / (__expf(2.f * x) + 1.f);
}
__device__ __forceinline__ float sigmoid_fast(float x) {
    return 1.f / (1.f + __expf(-x));
}

// Coherent (cross-XCD) scalar accesses: relaxed agent-scope atomics compile to
// sc0/sc1-flagged loads/stores that bypass the non-coherent per-XCD L2 for the
// communicated data ONLY — no buffer_inv/buffer_wbl2, weights stay L2-hot.
__device__ __forceinline__ float coh_ld(const float* p) {
    return __hip_atomic_load((const float*)p, __ATOMIC_RELAXED, __HIP_MEMORY_SCOPE_AGENT);
}
__device__ __forceinline__ void coh_st(float* p, float v) {
    __hip_atomic_store(p, v, __ATOMIC_RELAXED, __HIP_MEMORY_SCOPE_AGENT);
}

// ---------------------------------------------------------------------------
// Gather teacher-forced embeddings
__global__ void gather_emb(const int* __restrict__ tgt,
                           const float* __restrict__ emb,
                           float* __restrict__ out) {
    int r = blockIdx.x;
    int b = r >> 6, s = r & 63;
    int id = (s == 0) ? 1 : tgt[b * SS + (s - 1)];
    const float* ep = emb + (size_t)id * HH;
    float* op = out + (size_t)r * HH;
    op[threadIdx.x] = ep[threadIdx.x];
    op[threadIdx.x + 256] = ep[threadIdx.x + 256];
}

// ---------------------------------------------------------------------------
// Generic fp32 GEMM: C[M,N] = A[M,K] @ B[N,K]^T + bias[N]
__global__ __launch_bounds__(256) void gemm_bias(
    const float* __restrict__ A, int lda,
    const float* __restrict__ Bm, int ldb,
    const float* __restrict__ bias,
    float* __restrict__ C, int ldc, int K) {
    __shared__ float As[16][65];
    __shared__ float Bs[16][65];
    int tid = threadIdx.x;
    int tx = tid & 15, ty = tid >> 4;
    int m0 = blockIdx.y * 64, n0 = blockIdx.x * 64;
    float acc[4][4] = {};
    for (int k0 = 0; k0 < K; k0 += 16) {
#pragma unroll
        for (int i = 0; i < 4; i++) {
            int idx = tid + i * 256;
            int r = idx >> 4, kk = idx & 15;
            As[kk][r] = A[(size_t)(m0 + r) * lda + k0 + kk];
            Bs[kk][r] = Bm[(size_t)(n0 + r) * ldb + k0 + kk];
        }
        __syncthreads();
#pragma unroll
        for (int kk = 0; kk < 16; kk++) {
            float a[4], bv[4];
#pragma unroll
            for (int i = 0; i < 4; i++) a[i] = As[kk][ty * 4 + i];
#pragma unroll
            for (int j = 0; j < 4; j++) bv[j] = Bs[kk][tx * 4 + j];
#pragma unroll
            for (int i = 0; i < 4; i++)
#pragma unroll
                for (int j = 0; j < 4; j++) acc[i][j] += a[i] * bv[j];
        }
        __syncthreads();
    }
#pragma unroll
    for (int i = 0; i < 4; i++) {
        int m = m0 + ty * 4 + i;
#pragma unroll
        for (int j = 0; j < 4; j++) {
            int n = n0 + tx * 4 + j;
            C[(size_t)m * ldc + n] = acc[i][j] + bias[n];
        }
    }
}

// ---------------------------------------------------------------------------
// Cross-block generation barrier for an 8-block group (monotonic counter).
// FENCELESS: data travels via sc1-coherent stores/loads; all waves drain
// vmcnt before s_barrier, so thread 0's relaxed arrive-add is ordered after
// every wave's published data. No L2 invalidate, no L2 writeback.
__device__ __forceinline__ void group_bar(int* ctr, int target) {
    asm volatile("s_waitcnt vmcnt(0)" ::: "memory");
    __syncthreads();
    if (threadIdx.x == 0) {
        __hip_atomic_fetch_add(ctr, 1, __ATOMIC_RELAXED, __HIP_MEMORY_SCOPE_AGENT);
        while (__hip_atomic_load(ctr, __ATOMIC_RELAXED, __HIP_MEMORY_SCOPE_AGENT) < target)
            __builtin_amdgcn_s_sleep(1);
    }
    __syncthreads();
    asm volatile("" ::: "memory");  // keep coherent data loads after the spin
}

// ---------------------------------------------------------------------------
// Distributed recurrence: 256 blocks = 32 batch x 8 slices, 256 threads.
// Slice sl of batch b owns h/ctx/q indices [64*sl, 64*sl+64) and k-slices the
// gate GEMV. h-update is computed REDUNDANTLY by all 8 blocks (cheaper than a
// third cross-XCD barrier), so h lives in LDS and never round-trips globally.
__global__ __launch_bounds__(256) void recur2(
    const float* __restrict__ enc,      // [B,T,H]
    const float* __restrict__ enc_hid,  // [1,B,H]
    const float* __restrict__ Wa_w, const float* __restrict__ Wa_b,
    const float* __restrict__ Va_w, const float* __restrict__ Va_b,
    const float* __restrict__ W_ih,     // [3H, 2H]
    const float* __restrict__ W_hh,     // [3H, H]
    const float* __restrict__ b_hh,
    const float* __restrict__ ua,       // [B,T,H]
    const float* __restrict__ gie,      // [B*S, 3H] (includes b_ih)
    int* __restrict__ sync,             // [B*64] zeroed counters (256B stride)
    float* __restrict__ scp,            // [NSL][B][TT] score partials
    float* __restrict__ gp,             // [NSL][B][2048] gate partials
    float* __restrict__ hs,             // [B*S, H] all hidden states
    float* __restrict__ out_hT,         // [B,H]
    float* __restrict__ out_attn) {     // [B,S,T]
    int blk = blockIdx.x;
    int b = blk >> 3, sl = blk & 7;
    int tid = threadIdx.x;
    int w = tid >> 6, lane = tid & 63;

    __shared__ __align__(16) float sh_h[HH];
    __shared__ __align__(16) float sh_q[64];
    __shared__ __align__(16) float sh_ctx[64];
    __shared__ float sh_sc[TT], sh_w[TT];
    __shared__ float sh_cp[4][64];

    int* ctr = sync + b * 64;           // 256B-padded counter per batch group
    int bc = 0;
    float* scp_b = scp + (size_t)(sl * BB + b) * TT;
    float* gp_b  = gp  + (size_t)(sl * BB + b) * 2048;

    // initial hidden state
    sh_h[tid] = enc_hid[b * HH + tid];
    sh_h[tid + 256] = enc_hid[b * HH + tid + 256];

    for (int s = 0; s < SS; s++) {
        __syncthreads();   // sh_h ready (from init or previous Phase 6)

        // ---- Phase 1: my 64 q rows (wave-per-row, float4 coalesced)
        {
            const float4* h4 = (const float4*)sh_h;
            float4 h0 = h4[lane], h1 = h4[64 + lane];
            for (int r = 0; r < 16; r++) {
                int o = 64 * sl + w * 16 + r;
                const float4* wp = (const float4*)(Wa_w + (size_t)o * HH);
                float4 a0 = wp[lane], a1 = wp[64 + lane];
                float acc = a0.x * h0.x + a0.y * h0.y + a0.z * h0.z + a0.w * h0.w
                          + a1.x * h1.x + a1.y * h1.y + a1.z * h1.z + a1.w * h1.w;
#pragma unroll
                for (int off = 32; off; off >>= 1) acc += __shfl_xor(acc, off);
                if (lane == 0) sh_q[w * 16 + r] = acc + Wa_b[o];
            }
        }
        __syncthreads();

        // ---- Phase 2: partial scores over my o-range, all 128 t
        {
            float va = Va_w[64 * sl + lane];
            float myq = sh_q[lane];
            const float* uab = ua + ((size_t)b * TT + w * 32) * HH + 64 * sl + lane;
            for (int tt = 0; tt < 32; tt++) {
                float x = tanh_fast(myq + uab[(size_t)tt * HH]) * va;
#pragma unroll
                for (int off = 32; off; off >>= 1) x += __shfl_xor(x, off);
                if (lane == 0) coh_st(scp_b + w * 32 + tt, x);
            }
        }
        bc += NSL; group_bar(ctr, bc);   // scores published

        // ---- Phase 3: redundant softmax (cheap), slice 0 emits attention
        if (tid < TT) {
            float sc = Va_b[0];
#pragma unroll
            for (int s2 = 0; s2 < NSL; s2++)
                sc += coh_ld(scp + (size_t)(s2 * BB + b) * TT + tid);
            sh_sc[tid] = sc;
        }
        __syncthreads();
        if (tid < 64) {
            float a = sh_sc[tid], c = sh_sc[tid + 64];
            float m = fmaxf(a, c);
            for (int off = 32; off; off >>= 1) m = fmaxf(m, __shfl_xor(m, off));
            float ea = __expf(a - m), ec = __expf(c - m);
            float ssum = ea + ec;
            for (int off = 32; off; off >>= 1) ssum += __shfl_xor(ssum, off);
            float inv = 1.f / ssum;
            sh_w[tid] = ea * inv;
            sh_w[tid + 64] = ec * inv;
            if (sl == 0) {
                float* ap = out_attn + ((size_t)(b * SS + s)) * TT;
                ap[tid] = ea * inv;
                ap[tid + 64] = ec * inv;
            }
        }
        __syncthreads();

        // ---- Phase 4: my 64 ctx rows (coalesced over i, split t across waves)
        {
            const float* ep = enc + ((size_t)b * TT + w * 32) * HH + 64 * sl + lane;
            float acc = 0.f;
#pragma unroll 8
            for (int t2 = 0; t2 < 32; t2++) acc += sh_w[w * 32 + t2] * ep[(size_t)t2 * HH];
            sh_cp[w][lane] = acc;
        }
        __syncthreads();
        if (tid < 64) sh_ctx[tid] = sh_cp[0][tid] + sh_cp[1][tid] + sh_cp[2][tid] + sh_cp[3][tid];
        __syncthreads();

        // ---- Phase 5: k-sliced gate partials for ALL 1536 rows
        {
            int sub = lane & 15, r4 = lane >> 4;
            float4 cx = *(const float4*)&sh_ctx[sub * 4];
            float4 hx = *(const float4*)&sh_h[64 * sl + sub * 4];
            const float* gie_row = gie + ((size_t)(b * SS + s)) * 1536;
#pragma unroll 4
            for (int it = 0; it < 96; it++) {
                int j = w * 384 + it * 4 + r4;
                const float4 wi = *(const float4*)(W_ih + (size_t)j * 1024 + 512 + 64 * sl + sub * 4);
                const float4 wh = *(const float4*)(W_hh + (size_t)j * 512 + 64 * sl + sub * 4);
                float gi = wi.x * cx.x + wi.y * cx.y + wi.z * cx.z + wi.w * cx.w;
                float gh = wh.x * hx.x + wh.y * hx.y + wh.z * hx.z + wh.w * hx.w;
#pragma unroll
                for (int off = 1; off < 16; off <<= 1) {
                    gi += __shfl_xor(gi, off);
                    gh += __shfl_xor(gh, off);
                }
                if (sub == 0) {
                    if (j < 1024) {
                        float v = gi + gh;
                        if (sl == 0) v += gie_row[j] + b_hh[j];
                        coh_st(gp_b + j, v);
                    } else {
                        float vi = gi, vh = gh;
                        if (sl == 0) { vi += gie_row[j]; vh += b_hh[j]; }
                        coh_st(gp_b + j, vi);          // gin region [1024,1536)
                        coh_st(gp_b + j + 512, vh);    // ghn region [1536,2048)
                    }
                }
            }
        }
        bc += NSL; group_bar(ctr, bc);   // gate partials published

        // ---- Phase 6: FULL h update, computed redundantly by every block.
        // Thread t handles dims t and t+256: 64 pipelined coherent loads.
        {
            float rp0 = 0.f, zp0 = 0.f, gn0 = 0.f, hn0 = 0.f;
            float rp1 = 0.f, zp1 = 0.f, gn1 = 0.f, hn1 = 0.f;
#pragma unroll
            for (int s2 = 0; s2 < NSL; s2++) {
                const float* g = gp + (size_t)(s2 * BB + b) * 2048;
                rp0 += coh_ld(g + tid);
                zp0 += coh_ld(g + 512 + tid);
                gn0 += coh_ld(g + 1024 + tid);
                hn0 += coh_ld(g + 1536 + tid);
                rp1 += coh_ld(g + 256 + tid);
                zp1 += coh_ld(g + 768 + tid);
                gn1 += coh_ld(g + 1280 + tid);
                hn1 += coh_ld(g + 1792 + tid);
            }
            float r0 = sigmoid_fast(rp0), z0 = sigmoid_fast(zp0);
            float n0 = tanh_fast(gn0 + r0 * hn0);
            float h0 = (1.f - z0) * n0 + z0 * sh_h[tid];
            float r1 = sigmoid_fast(rp1), z1 = sigmoid_fast(zp1);
            float n1 = tanh_fast(gn1 + r1 * hn1);
            float h1 = (1.f - z1) * n1 + z1 * sh_h[tid + 256];
            sh_h[tid] = h0;
            sh_h[tid + 256] = h1;
            // publish owned slice to hs (consumed only by the post-kernel GEMM)
            float* hrow = hs + ((size_t)(b * SS + s)) * HH;
            if ((tid >> 6) == sl) hrow[tid] = h0;
            if (((tid + 256) >> 6) == sl) hrow[tid + 256] = h1;
            if (s == SS - 1) {
                if ((tid >> 6) == sl) out_hT[b * HH + tid] = h0;
                if (((tid + 256) >> 6) == sl) out_hT[b * HH + tid + 256] = h1;
            }
        }
    }
}

// ---------------------------------------------------------------------------
// In-place log_softmax over rows of 32000
__global__ __launch_bounds__(256) void lse_kernel(float* __restrict__ logits) {
    int row = blockIdx.x;
    float* rp = logits + (size_t)row * VV;
    int tid = threadIdx.x;
    __shared__ float red[4];
    __shared__ float bc;
    float m = -INFINITY;
    for (int i = tid; i < VV; i += 256) m = fmaxf(m, rp[i]);
    for (int off = 32; off; off >>= 1) m = fmaxf(m, __shfl_xor(m, off));
    if ((tid & 63) == 0) red[tid >> 6] = m;
    __syncthreads();
    if (tid == 0) bc = fmaxf(fmaxf(red[0], red[1]), fmaxf(red[2], red[3]));
    __syncthreads();
    m = bc;
    float ssum = 0.f;
    for (int i = tid; i < VV; i += 256) ssum += __expf(rp[i] - m);
    for (int off = 32; off; off >>= 1) ssum += __shfl_xor(ssum, off);
    if ((tid & 63) == 0) red[tid >> 6] = ssum;
    __syncthreads();
    if (tid == 0) bc = m + logf(red[0] + red[1] + red[2] + red[3]);
    __syncthreads();
    float lse = bc;
    for (int i = tid; i < VV; i += 256) rp[i] -= lse;
}

// ---------------------------------------------------------------------------
extern "C" void kernel_launch(void* const* d_in, const int* in_sizes, int n_in,
                              void* d_out, int out_size, void* d_ws, size_t ws_size,
                              hipStream_t stream) {
    const float* enc     = (const float*)d_in[0];
    const float* enc_hid = (const float*)d_in[1];
    const int*   tgt     = (const int*)d_in[2];
    const float* emb     = (const float*)d_in[3];
    const float* Wa_w    = (const float*)d_in[4];
    const float* Wa_b    = (const float*)d_in[5];
    const float* Ua_w    = (const float*)d_in[6];
    const float* Ua_b    = (const float*)d_in[7];
    const float* Va_w    = (const float*)d_in[8];
    const float* Va_b    = (const float*)d_in[9];
    const float* W_ih    = (const float*)d_in[10];
    const float* W_hh    = (const float*)d_in[11];
    const float* b_ih    = (const float*)d_in[12];
    const float* b_hh    = (const float*)d_in[13];
    const float* out_w   = (const float*)d_in[14];
    const float* out_b   = (const float*)d_in[15];
    float* out = (float*)d_out;

    float* ws      = (float*)d_ws;
    float* ws_emb  = ws;                          // 2048*512  (reused by recur scratch)
    float* ws_ua   = ws_emb + 2048 * 512;         // 4096*512
    float* ws_gie  = ws_ua + 4096 * 512;          // 2048*1536
    float* ws_hs   = ws_gie + 2048 * 1536;        // 2048*512
    // recur-time aliases of the (consumed) emb region:
    int*   ws_sync = (int*)ws;                    // 32 counters, 64-int stride (8KB)
    float* ws_scp  = ws + 2048;                   // 8*32*128
    float* ws_gp   = ws + 2048 + NSL * BB * TT;   // 8*32*2048

    float* out_logits = out;                                  // [B*S, V]
    float* out_hT     = out + (size_t)BB * SS * VV;           // [B, H]
    float* out_attn   = out_hT + (size_t)BB * HH;             // [B, S, T]

    gather_emb<<<dim3(2048), dim3(256), 0, stream>>>(tgt, emb, ws_emb);
    gemm_bias<<<dim3(8, 64), dim3(256), 0, stream>>>(
        enc, HH, Ua_w, HH, Ua_b, ws_ua, HH, HH);
    gemm_bias<<<dim3(24, 32), dim3(256), 0, stream>>>(
        ws_emb, HH, W_ih, 2 * HH, b_ih, ws_gie, 3 * HH, HH);
    // zero the barrier counters (after the gie GEMM consumed the emb region)
    hipMemsetAsync(d_ws, 0, 8192, stream);
    recur2<<<dim3(BB * NSL), dim3(256), 0, stream>>>(
        enc, enc_hid, Wa_w, Wa_b, Va_w, Va_b, W_ih, W_hh, b_hh,
        ws_ua, ws_gie, ws_sync, ws_scp, ws_gp, ws_hs, out_hT, out_attn);
    gemm_bias<<<dim3(500, 32), dim3(256), 0, stream>>>(
        ws_hs, HH, out_w, HH, out_b, out_logits, VV, HH);
    lse_kernel<<<dim3(2048), dim3(256), 0, stream>>>(out_logits);
}

// Round 2
// 9382.210 us; speedup vs baseline: 1.0763x; 1.0763x over previous
//
#include <hip/hip_runtime.h>
#include <hip/hip_bf16.h>
#include <math.h>

// Problem constants
#define BB 32     // batch
#define TT 128    // encoder timesteps
#define HH 512    // hidden
#define VV 32000  // vocab
#define SS 64     // decode steps (BLOCK)
#define NSL 8     // slices (blocks) per batch element

__device__ __forceinline__ float tanh_fast(float x) {
    return 1.f - 2.f / (__expf(2.f * x) + 1.f);
}
__device__ __forceinline__ float sigmoid_fast(float x) {
    return 1.f / (1.f + __expf(-x));
}

// Coherent (cross-XCD) accesses. These bypass the non-coherent per-XCD L2 and
// go to the coherence point — use ONLY for cross-block communicated data.
__device__ __forceinline__ float coh_ld(const float* p) {
    return __hip_atomic_load((const float*)p, __ATOMIC_RELAXED, __HIP_MEMORY_SCOPE_AGENT);
}
__device__ __forceinline__ void coh_st(float* p, float v) {
    __hip_atomic_store(p, v, __ATOMIC_RELAXED, __HIP_MEMORY_SCOPE_AGENT);
}
// Fire-and-forget fp32 accumulate at agent scope (no return value).
__device__ __forceinline__ void atom_add(float* p, float v) {
    __hip_atomic_fetch_add(p, v, __ATOMIC_RELAXED, __HIP_MEMORY_SCOPE_AGENT);
}

// ---------------------------------------------------------------------------
// Gather teacher-forced embeddings
__global__ void gather_emb(const int* __restrict__ tgt,
                           const float* __restrict__ emb,
                           float* __restrict__ out) {
    int r = blockIdx.x;
    int b = r >> 6, s = r & 63;
    int id = (s == 0) ? 1 : tgt[b * SS + (s - 1)];
    const float* ep = emb + (size_t)id * HH;
    float* op = out + (size_t)r * HH;
    op[threadIdx.x] = ep[threadIdx.x];
    op[threadIdx.x + 256] = ep[threadIdx.x + 256];
}

// ---------------------------------------------------------------------------
// Generic fp32 GEMM: C[M,N] = A[M,K] @ B[N,K]^T + bias[N]
__global__ __launch_bounds__(256) void gemm_bias(
    const float* __restrict__ A, int lda,
    const float* __restrict__ Bm, int ldb,
    const float* __restrict__ bias,
    float* __restrict__ C, int ldc, int K) {
    __shared__ float As[16][65];
    __shared__ float Bs[16][65];
    int tid = threadIdx.x;
    int tx = tid & 15, ty = tid >> 4;
    int m0 = blockIdx.y * 64, n0 = blockIdx.x * 64;
    float acc[4][4] = {};
    for (int k0 = 0; k0 < K; k0 += 16) {
#pragma unroll
        for (int i = 0; i < 4; i++) {
            int idx = tid + i * 256;
            int r = idx >> 4, kk = idx & 15;
            As[kk][r] = A[(size_t)(m0 + r) * lda + k0 + kk];
            Bs[kk][r] = Bm[(size_t)(n0 + r) * ldb + k0 + kk];
        }
        __syncthreads();
#pragma unroll
        for (int kk = 0; kk < 16; kk++) {
            float a[4], bv[4];
#pragma unroll
            for (int i = 0; i < 4; i++) a[i] = As[kk][ty * 4 + i];
#pragma unroll
            for (int j = 0; j < 4; j++) bv[j] = Bs[kk][tx * 4 + j];
#pragma unroll
            for (int i = 0; i < 4; i++)
#pragma unroll
                for (int j = 0; j < 4; j++) acc[i][j] += a[i] * bv[j];
        }
        __syncthreads();
    }
#pragma unroll
    for (int i = 0; i < 4; i++) {
        int m = m0 + ty * 4 + i;
#pragma unroll
        for (int j = 0; j < 4; j++) {
            int n = n0 + tx * 4 + j;
            C[(size_t)m * ldc + n] = acc[i][j] + bias[n];
        }
    }
}

// ---------------------------------------------------------------------------
// Cross-block generation barrier for an 8-block group (monotonic counter).
// FENCELESS: communicated data travels via coherent atomics; all waves drain
// vmcnt before s_barrier, so thread 0's relaxed arrive-add is ordered after
// every wave's published data. No L2 invalidate, no L2 writeback -> weights
// stay L2-hot across the whole kernel.
__device__ __forceinline__ void group_bar(int* ctr, int target) {
    asm volatile("s_waitcnt vmcnt(0)" ::: "memory");
    __syncthreads();
    if (threadIdx.x == 0) {
        __hip_atomic_fetch_add(ctr, 1, __ATOMIC_RELAXED, __HIP_MEMORY_SCOPE_AGENT);
        while (__hip_atomic_load(ctr, __ATOMIC_RELAXED, __HIP_MEMORY_SCOPE_AGENT) < target)
            __builtin_amdgcn_s_sleep(1);
    }
    __syncthreads();
    asm volatile("" ::: "memory");  // keep coherent data loads after the spin
}

// ---------------------------------------------------------------------------
// Distributed recurrence: 256 blocks = 32 batch x 8 slices, 256 threads.
// Slice sl of batch b owns h/q/ctx dims [64*sl, 64*sl+64).
// Cross-block reductions (q, scores, gates) go through per-batch fp32
// atomicAdd accumulators: each consumer reads ONE summed value instead of 8
// partials, and re-zeroes it in place for the next step. Full h is never
// materialized: next-step q contributions (qp = Wa[:,own]·h_own) are pushed
// from each slice's own h, so W_hh·h and z·h only need the own 64 dims.
__global__ __launch_bounds__(256) void recur3(
    const float* __restrict__ enc,      // [B,T,H]
    const float* __restrict__ enc_hid,  // [1,B,H]
    const float* __restrict__ Wa_w, const float* __restrict__ Wa_b,
    const float* __restrict__ Va_w, const float* __restrict__ Va_b,
    const float* __restrict__ W_ih,     // [3H, 2H]
    const float* __restrict__ W_hh,     // [3H, H]
    const float* __restrict__ b_hh,
    const float* __restrict__ ua,       // [B,T,H]
    const float* __restrict__ gie,      // [B*S, 3H] (includes b_ih)
    int* __restrict__ sync,             // [B*64] zeroed counters (256B stride)
    float* __restrict__ qacc,           // [B][512]  zero-init accumulators
    float* __restrict__ sacc,           // [B][128]  zero-init
    float* __restrict__ gacc,           // [B][2048] zero-init
    float* __restrict__ hs,             // [B*S, H] all hidden states
    float* __restrict__ out_hT,         // [B,H]
    float* __restrict__ out_attn) {     // [B,S,T]
    int blk = blockIdx.x;
    int b = blk >> 3, sl = blk & 7;
    int tid = threadIdx.x;
    int w = tid >> 6, lane = tid & 63;

    __shared__ __align__(16) float sh_h[64];    // own h slice
    __shared__ __align__(16) float sh_q[64];    // own q slice (o-range)
    __shared__ __align__(16) float sh_ctx[64];  // own ctx slice
    __shared__ float sh_sc[TT], sh_w[TT];
    __shared__ float sh_cp[4][64];
    __shared__ float sh_g[4][64];               // summed gates for own dims

    int* ctr = sync + b * 64;                   // 256B-padded counter per group
    int bc = 0;
    float* qac = qacc + (size_t)b * 512;
    float* sac = sacc + (size_t)b * 128;
    float* gac = gacc + (size_t)b * 2048;

    // initial own hidden slice
    if (tid < 64) sh_h[tid] = enc_hid[b * HH + 64 * sl + tid];
    __syncthreads();

    int sub = lane & 15, grp = lane >> 4;       // 16-lane k-groups, 4 per wave

    for (int s = 0; s < SS; s++) {
        // ---- Phase Q: push q contributions for this step from own h slice.
        // qp[o] = sum_{k in own64} Wa_w[o,k] * h[k], for ALL 512 o.
        {
            float4 hx = *(const float4*)&sh_h[sub * 4];
#pragma unroll 4
            for (int it = 0; it < 32; it++) {
                int o = w * 128 + it * 4 + grp;
                const float4 wv = *(const float4*)(Wa_w + (size_t)o * HH + 64 * sl + sub * 4);
                float acc = wv.x * hx.x + wv.y * hx.y + wv.z * hx.z + wv.w * hx.w;
#pragma unroll
                for (int off = 1; off < 16; off <<= 1) acc += __shfl_xor(acc, off);
                if (sub == 0) atom_add(qac + o, acc);
            }
        }
        bc += NSL; group_bar(ctr, bc);   // Bq: qacc complete

        // ---- read own q (+bias) and rezero accumulator for next step
        if (tid < 64) {
            int o = 64 * sl + tid;
            float qv = coh_ld(qac + o);
            coh_st(qac + o, 0.f);
            sh_q[tid] = qv + Wa_b[o];
        }
        __syncthreads();

        // ---- Phase S: score partials over own o-range, all 128 t (pushed)
        {
            float va = Va_w[64 * sl + lane];
            float myq = sh_q[lane];
            const float* uab = ua + ((size_t)b * TT + w * 32) * HH + 64 * sl + lane;
#pragma unroll 4
            for (int tt = 0; tt < 32; tt++) {
                float x = tanh_fast(myq + uab[(size_t)tt * HH]) * va;
#pragma unroll
                for (int off = 32; off; off >>= 1) x += __shfl_xor(x, off);
                if (lane == 0) atom_add(sac + w * 32 + tt, x);
            }
        }
        bc += NSL; group_bar(ctr, bc);   // Bs: sacc complete

        // ---- softmax (redundant per block, cheap); slice 0 emits attention
        if (tid < TT) sh_sc[tid] = coh_ld(sac + tid) + Va_b[0];
        __syncthreads();
        if (tid < 64) {
            float a = sh_sc[tid], c = sh_sc[tid + 64];
            float m = fmaxf(a, c);
            for (int off = 32; off; off >>= 1) m = fmaxf(m, __shfl_xor(m, off));
            float ea = __expf(a - m), ec = __expf(c - m);
            float ssum = ea + ec;
            for (int off = 32; off; off >>= 1) ssum += __shfl_xor(ssum, off);
            float inv = 1.f / ssum;
            sh_w[tid] = ea * inv;
            sh_w[tid + 64] = ec * inv;
            if (sl == 0) {
                float* ap = out_attn + ((size_t)(b * SS + s)) * TT;
                ap[tid] = ea * inv;
                ap[tid + 64] = ec * inv;
            }
        }
        __syncthreads();

        // ---- Phase C: own 64 ctx dims (coalesced over i, split t across waves)
        {
            const float* ep = enc + ((size_t)b * TT + w * 32) * HH + 64 * sl + lane;
            float acc = 0.f;
#pragma unroll 8
            for (int t2 = 0; t2 < 32; t2++) acc += sh_w[w * 32 + t2] * ep[(size_t)t2 * HH];
            sh_cp[w][lane] = acc;
        }
        __syncthreads();
        if (tid < 64) sh_ctx[tid] = sh_cp[0][tid] + sh_cp[1][tid] + sh_cp[2][tid] + sh_cp[3][tid];
        __syncthreads();

        // ---- Phase G: k-sliced gate partials for ALL 1536 rows (pushed)
        {
            float4 cx = *(const float4*)&sh_ctx[sub * 4];
            float4 hx = *(const float4*)&sh_h[sub * 4];
            const float* gie_row = gie + ((size_t)(b * SS + s)) * 1536;
#pragma unroll 4
            for (int it = 0; it < 96; it++) {
                int j = w * 384 + it * 4 + grp;
                const float4 wi = *(const float4*)(W_ih + (size_t)j * 1024 + 512 + 64 * sl + sub * 4);
                const float4 wh = *(const float4*)(W_hh + (size_t)j * 512 + 64 * sl + sub * 4);
                float gi = wi.x * cx.x + wi.y * cx.y + wi.z * cx.z + wi.w * cx.w;
                float gh = wh.x * hx.x + wh.y * hx.y + wh.z * hx.z + wh.w * hx.w;
#pragma unroll
                for (int off = 1; off < 16; off <<= 1) {
                    gi += __shfl_xor(gi, off);
                    gh += __shfl_xor(gh, off);
                }
                if (sub == 0) {
                    if (j < 1024) {
                        float v = gi + gh;
                        if (sl == 0) v += gie_row[j] + b_hh[j];
                        atom_add(gac + j, v);
                    } else {
                        float vi = gi, vh = gh;
                        if (sl == 0) { vi += gie_row[j]; vh += b_hh[j]; }
                        atom_add(gac + j, vi);          // gin region [1024,1536)
                        atom_add(gac + j + 512, vh);    // ghn region [1536,2048)
                    }
                }
            }
        }
        bc += NSL; group_bar(ctr, bc);   // Bg: gacc complete

        // ---- Phase H: read own 256 gate sums (+rezero), GRU update own dims
        {
            int c = tid >> 6, d = tid & 63;
            int idx = c * 512 + 64 * sl + d;
            float v = coh_ld(gac + idx);
            coh_st(gac + idx, 0.f);
            sh_g[c][d] = v;
            // rezero my slice of the score accumulator (all readers drained at Bg)
            if (tid < 16) coh_st(sac + 16 * sl + tid, 0.f);
        }
        __syncthreads();
        if (tid < 64) {
            float r = sigmoid_fast(sh_g[0][tid]);
            float z = sigmoid_fast(sh_g[1][tid]);
            float n = tanh_fast(sh_g[2][tid] + r * sh_g[3][tid]);
            float hn = (1.f - z) * n + z * sh_h[tid];
            sh_h[tid] = hn;
            hs[((size_t)(b * SS + s)) * HH + 64 * sl + tid] = hn;
            if (s == SS - 1) out_hT[b * HH + 64 * sl + tid] = hn;
        }
        __syncthreads();
    }
}

// ---------------------------------------------------------------------------
// In-place log_softmax over rows of 32000
__global__ __launch_bounds__(256) void lse_kernel(float* __restrict__ logits) {
    int row = blockIdx.x;
    float* rp = logits + (size_t)row * VV;
    int tid = threadIdx.x;
    __shared__ float red[4];
    __shared__ float bc;
    float m = -INFINITY;
    for (int i = tid; i < VV; i += 256) m = fmaxf(m, rp[i]);
    for (int off = 32; off; off >>= 1) m = fmaxf(m, __shfl_xor(m, off));
    if ((tid & 63) == 0) red[tid >> 6] = m;
    __syncthreads();
    if (tid == 0) bc = fmaxf(fmaxf(red[0], red[1]), fmaxf(red[2], red[3]));
    __syncthreads();
    m = bc;
    float ssum = 0.f;
    for (int i = tid; i < VV; i += 256) ssum += __expf(rp[i] - m);
    for (int off = 32; off; off >>= 1) ssum += __shfl_xor(ssum, off);
    if ((tid & 63) == 0) red[tid >> 6] = ssum;
    __syncthreads();
    if (tid == 0) bc = m + logf(red[0] + red[1] + red[2] + red[3]);
    __syncthreads();
    float lse = bc;
    for (int i = tid; i < VV; i += 256) rp[i] -= lse;
}

// ---------------------------------------------------------------------------
extern "C" void kernel_launch(void* const* d_in, const int* in_sizes, int n_in,
                              void* d_out, int out_size, void* d_ws, size_t ws_size,
                              hipStream_t stream) {
    const float* enc     = (const float*)d_in[0];
    const float* enc_hid = (const float*)d_in[1];
    const int*   tgt     = (const int*)d_in[2];
    const float* emb     = (const float*)d_in[3];
    const float* Wa_w    = (const float*)d_in[4];
    const float* Wa_b    = (const float*)d_in[5];
    const float* Ua_w    = (const float*)d_in[6];
    const float* Ua_b    = (const float*)d_in[7];
    const float* Va_w    = (const float*)d_in[8];
    const float* Va_b    = (const float*)d_in[9];
    const float* W_ih    = (const float*)d_in[10];
    const float* W_hh    = (const float*)d_in[11];
    const float* b_ih    = (const float*)d_in[12];
    const float* b_hh    = (const float*)d_in[13];
    const float* out_w   = (const float*)d_in[14];
    const float* out_b   = (const float*)d_in[15];
    float* out = (float*)d_out;

    float* ws      = (float*)d_ws;
    float* ws_emb  = ws;                          // 2048*512  (reused by recur scratch)
    float* ws_ua   = ws_emb + 2048 * 512;         // 4096*512
    float* ws_gie  = ws_ua + 4096 * 512;          // 2048*1536
    float* ws_hs   = ws_gie + 2048 * 1536;        // 2048*512
    // recur-time aliases of the (consumed) emb region:
    int*   ws_sync = (int*)ws;                    // 32 counters, 64-int stride (8KB)
    float* ws_qacc = ws + 2048;                   // 32*512
    float* ws_sacc = ws_qacc + BB * 512;          // 32*128
    float* ws_gacc = ws_sacc + BB * 128;          // 32*2048
    // total scratch floats: 2048 + 16384 + 4096 + 65536 = 88064 (< 1M region)

    float* out_logits = out;                                  // [B*S, V]
    float* out_hT     = out + (size_t)BB * SS * VV;           // [B, H]
    float* out_attn   = out_hT + (size_t)BB * HH;             // [B, S, T]

    gather_emb<<<dim3(2048), dim3(256), 0, stream>>>(tgt, emb, ws_emb);
    gemm_bias<<<dim3(8, 64), dim3(256), 0, stream>>>(
        enc, HH, Ua_w, HH, Ua_b, ws_ua, HH, HH);
    gemm_bias<<<dim3(24, 32), dim3(256), 0, stream>>>(
        ws_emb, HH, W_ih, 2 * HH, b_ih, ws_gie, 3 * HH, HH);
    // zero counters + q/s/g accumulators (after the gie GEMM consumed emb)
    hipMemsetAsync(d_ws, 0, 88064 * 4, stream);
    recur3<<<dim3(BB * NSL), dim3(256), 0, stream>>>(
        enc, enc_hid, Wa_w, Wa_b, Va_w, Va_b, W_ih, W_hh, b_hh,
        ws_ua, ws_gie, ws_sync, ws_qacc, ws_sacc, ws_gacc, ws_hs, out_hT, out_attn);
    gemm_bias<<<dim3(500, 32), dim3(256), 0, stream>>>(
        ws_hs, HH, out_w, HH, out_b, out_logits, VV, HH);
    lse_kernel<<<dim3(2048), dim3(256), 0, stream>>>(out_logits);
}

// Round 3
// 5713.576 us; speedup vs baseline: 1.7674x; 1.6421x over previous
//
#include <hip/hip_runtime.h>
#include <hip/hip_bf16.h>
#include <math.h>

// Problem constants
#define BB 32     // batch
#define TT 128    // encoder timesteps
#define HH 512    // hidden
#define VV 32000  // vocab
#define SS 64     // decode steps (BLOCK)
#define NSL 8     // slices (blocks) per batch element

__device__ __forceinline__ float tanh_fast(float x) {
    return 1.f - 2.f / (__expf(2.f * x) + 1.f);
}
__device__ __forceinline__ float sigmoid_fast(float x) {
    return 1.f / (1.f + __expf(-x));
}

// Coherent (cross-XCD) scalar accesses — bypass L1/L2, visible at IF.
__device__ __forceinline__ float coh_ld(const float* p) {
    return __hip_atomic_load((const float*)p, __ATOMIC_RELAXED, __HIP_MEMORY_SCOPE_AGENT);
}
__device__ __forceinline__ void coh_st(float* p, float v) {
    __hip_atomic_store(p, v, __ATOMIC_RELAXED, __HIP_MEMORY_SCOPE_AGENT);
}

// bf16 helpers (self-contained; RNE pack, shift-expand)
__device__ __forceinline__ unsigned short f2bf(float f) {
    unsigned int u = __float_as_uint(f);
    u = (u + 0x7fffu + ((u >> 16) & 1u)) >> 16;
    return (unsigned short)u;
}
__device__ __forceinline__ float bf2f(unsigned short h) {
    return __uint_as_float(((unsigned int)h) << 16);
}

// ---------------------------------------------------------------------------
// Gather teacher-forced embeddings
__global__ void gather_emb(const int* __restrict__ tgt,
                           const float* __restrict__ emb,
                           float* __restrict__ out) {
    int r = blockIdx.x;
    int b = r >> 6, s = r & 63;
    int id = (s == 0) ? 1 : tgt[b * SS + (s - 1)];
    const float* ep = emb + (size_t)id * HH;
    float* op = out + (size_t)r * HH;
    op[threadIdx.x] = ep[threadIdx.x];
    op[threadIdx.x + 256] = ep[threadIdx.x + 256];
}

// ---------------------------------------------------------------------------
// Weight pack kernels (fp32 -> bf16)
__global__ __launch_bounds__(256) void pack_plain_bf16(
    const float* __restrict__ src, unsigned short* __restrict__ dst, int n) {
    int i = blockIdx.x * 256 + threadIdx.x;
    if (i < n) dst[i] = f2bf(src[i]);
}
// W_ih ctx half: src [1536][1024] cols 512..1024 -> dst [1536][512]
__global__ __launch_bounds__(256) void pack_wih_bf16(
    const float* __restrict__ wih, unsigned short* __restrict__ dst) {
    int i = blockIdx.x * 256 + threadIdx.x;   // 1536*512 total
    int j = i >> 9, k = i & 511;
    dst[i] = f2bf(wih[(size_t)j * 1024 + 512 + k]);
}

// ---------------------------------------------------------------------------
// Generic fp32 GEMM: C[M,N] = A[M,K] @ B[N,K]^T + bias[N]
__global__ __launch_bounds__(256) void gemm_bias(
    const float* __restrict__ A, int lda,
    const float* __restrict__ Bm, int ldb,
    const float* __restrict__ bias,
    float* __restrict__ C, int ldc, int K) {
    __shared__ float As[16][65];
    __shared__ float Bs[16][65];
    int tid = threadIdx.x;
    int tx = tid & 15, ty = tid >> 4;
    int m0 = blockIdx.y * 64, n0 = blockIdx.x * 64;
    float acc[4][4] = {};
    for (int k0 = 0; k0 < K; k0 += 16) {
#pragma unroll
        for (int i = 0; i < 4; i++) {
            int idx = tid + i * 256;
            int r = idx >> 4, kk = idx & 15;
            As[kk][r] = A[(size_t)(m0 + r) * lda + k0 + kk];
            Bs[kk][r] = Bm[(size_t)(n0 + r) * ldb + k0 + kk];
        }
        __syncthreads();
#pragma unroll
        for (int kk = 0; kk < 16; kk++) {
            float a[4], bv[4];
#pragma unroll
            for (int i = 0; i < 4; i++) a[i] = As[kk][ty * 4 + i];
#pragma unroll
            for (int j = 0; j < 4; j++) bv[j] = Bs[kk][tx * 4 + j];
#pragma unroll
            for (int i = 0; i < 4; i++)
#pragma unroll
                for (int j = 0; j < 4; j++) acc[i][j] += a[i] * bv[j];
        }
        __syncthreads();
    }
#pragma unroll
    for (int i = 0; i < 4; i++) {
        int m = m0 + ty * 4 + i;
#pragma unroll
        for (int j = 0; j < 4; j++) {
            int n = n0 + tx * 4 + j;
            C[(size_t)m * ldc + n] = acc[i][j] + bias[n];
        }
    }
}

// ---------------------------------------------------------------------------
// Cross-block generation barrier for an 8-block group (monotonic counter).
// FENCELESS: data travels via coherent (sc0 sc1) ops; all waves drain vmcnt
// before s_barrier so the arrive-add is ordered after published data.
__device__ __forceinline__ void group_bar(int* ctr, int target) {
    asm volatile("s_waitcnt vmcnt(0)" ::: "memory");
    __syncthreads();
    if (threadIdx.x == 0) {
        __hip_atomic_fetch_add(ctr, 1, __ATOMIC_RELAXED, __HIP_MEMORY_SCOPE_AGENT);
        while (__hip_atomic_load(ctr, __ATOMIC_RELAXED, __HIP_MEMORY_SCOPE_AGENT) < target)
            __builtin_amdgcn_s_sleep(1);
    }
    __syncthreads();
    asm volatile("" ::: "memory");
}

// ---------------------------------------------------------------------------
// Distributed recurrence v4: 256 blocks = 32 batch x 8 slices, 256 threads.
// Row-sliced (not k-sliced): each block pulls FULL h / FULL ctx (512 floats,
// 2 coherent wave-loads) once per step and computes its own-64 q rows, own-64
// ctx dims and own-192 gate rows to completion locally. No data atomics, no
// fences; 3 tiny-payload barriers per step. Streamed weights are bf16.
__global__ __launch_bounds__(256) void recur4(
    const float* __restrict__ enc,        // [B,T,H] fp32
    const float* __restrict__ enc_hid,    // [1,B,H]
    const unsigned short* __restrict__ wa_h,   // [512][512] bf16
    const float* __restrict__ Wa_b,
    const float* __restrict__ Va_w, const float* __restrict__ Va_b,
    const unsigned short* __restrict__ wih_h,  // [1536][512] bf16 (ctx half)
    const unsigned short* __restrict__ whh_h,  // [1536][512] bf16
    const float* __restrict__ b_hh,
    const float* __restrict__ ua,         // [B,T,H] fp32
    const float* __restrict__ gie,        // [B*S, 3H] (includes b_ih)
    int* __restrict__ sync,               // [B*64] zeroed counters
    float* __restrict__ scp,              // [NSL][B][TT] score partials
    float* __restrict__ ctxc,             // [B][512] full ctx
    float* __restrict__ hcur,             // [B][512] full h
    float* __restrict__ hs,               // [B*S, H]
    float* __restrict__ out_hT,           // [B,H]
    float* __restrict__ out_attn) {       // [B,S,T]
    int blk = blockIdx.x;
    int b = blk >> 3, sl = blk & 7;
    int tid = threadIdx.x;
    int w = tid >> 6, lane = tid & 63;
    int grp = lane >> 4, sub = lane & 15;
    int pair = w * 4 + grp;               // 16 cooperative 16-lane groups

    __shared__ __align__(16) float sh_h[HH];
    __shared__ __align__(16) float sh_ctx[HH];
    __shared__ __align__(16) float sh_q[64];
    __shared__ float sh_sc[TT], sh_w[TT];
    __shared__ float sh_cp[4][64];
    __shared__ float sh_g[4][64];

    int* ctr = sync + b * 64;
    int bc = 0;

    // initial full hidden state
    sh_h[tid] = enc_hid[b * HH + tid];
    sh_h[tid + 256] = enc_hid[b * HH + tid + 256];

    for (int s = 0; s < SS; s++) {
        __syncthreads();   // sh_h complete (init or end-of-prev-step pull)

        // ---- P1: q own-64 rows = Wa[own,:] . h  (16-lane groups, 4 rows each)
        {
            float acc[4] = {0.f, 0.f, 0.f, 0.f};
#pragma unroll
            for (int i = 0; i < 4; i++) {
                int o = 64 * sl + pair * 4 + i;
                const unsigned short* wp = wa_h + (size_t)o * HH;
#pragma unroll
                for (int it = 0; it < 8; it++) {
                    int k0 = it * 64 + sub * 4;
                    ushort4 wv = *(const ushort4*)(wp + k0);
                    float4 hv = *(const float4*)&sh_h[k0];
                    acc[i] += bf2f(wv.x) * hv.x + bf2f(wv.y) * hv.y
                            + bf2f(wv.z) * hv.z + bf2f(wv.w) * hv.w;
                }
            }
#pragma unroll
            for (int i = 0; i < 4; i++)
#pragma unroll
                for (int off = 1; off < 16; off <<= 1) acc[i] += __shfl_xor(acc[i], off);
            if (sub == 0) {
#pragma unroll
                for (int i = 0; i < 4; i++) {
                    int r = pair * 4 + i;
                    sh_q[r] = acc[i] + Wa_b[64 * sl + r];
                }
            }
        }
        __syncthreads();

        // ---- P2: score partials: lane-per-own-o, wave-per-t-range, push
        {
            float va = Va_w[64 * sl + lane];
            float myq = sh_q[lane];
            const float* uab = ua + ((size_t)b * TT + w * 32) * HH + 64 * sl + lane;
            float* sc_out = scp + (size_t)(sl * BB + b) * TT + w * 32;
#pragma unroll 4
            for (int tt = 0; tt < 32; tt++) {
                float x = tanh_fast(myq + uab[(size_t)tt * HH]) * va;
#pragma unroll
                for (int off = 32; off; off >>= 1) x += __shfl_xor(x, off);
                if (lane == 0) coh_st(sc_out + tt, x);
            }
        }
        bc += NSL; group_bar(ctr, bc);   // Bs: score partials complete

        // ---- P3: redundant softmax; slice 0 emits attention
        if (tid < TT) {
            float sc = Va_b[0];
#pragma unroll
            for (int s2 = 0; s2 < NSL; s2++)
                sc += coh_ld(scp + (size_t)(s2 * BB + b) * TT + tid);
            sh_sc[tid] = sc;
        }
        __syncthreads();
        if (tid < 64) {
            float a = sh_sc[tid], c = sh_sc[tid + 64];
            float m = fmaxf(a, c);
            for (int off = 32; off; off >>= 1) m = fmaxf(m, __shfl_xor(m, off));
            float ea = __expf(a - m), ec = __expf(c - m);
            float ssum = ea + ec;
            for (int off = 32; off; off >>= 1) ssum += __shfl_xor(ssum, off);
            float inv = 1.f / ssum;
            sh_w[tid] = ea * inv;
            sh_w[tid + 64] = ec * inv;
            if (sl == 0) {
                float* ap = out_attn + ((size_t)(b * SS + s)) * TT;
                ap[tid] = ea * inv;
                ap[tid + 64] = ec * inv;
            }
        }
        __syncthreads();

        // ---- P4: ctx own-64 dims, push
        {
            const float* ep = enc + ((size_t)b * TT + w * 32) * HH + 64 * sl + lane;
            float acc = 0.f;
#pragma unroll 8
            for (int t2 = 0; t2 < 32; t2++) acc += sh_w[w * 32 + t2] * ep[(size_t)t2 * HH];
            sh_cp[w][lane] = acc;
        }
        __syncthreads();
        if (tid < 64) {
            float cv = sh_cp[0][tid] + sh_cp[1][tid] + sh_cp[2][tid] + sh_cp[3][tid];
            coh_st(ctxc + (size_t)b * HH + 64 * sl + tid, cv);
        }

        // ---- P6a: W_hh . h dots for own-192 rows (hoisted BEFORE ctx barrier)
        float ghr[12];
#pragma unroll
        for (int i = 0; i < 12; i++) {
            int ri = pair * 12 + i;                  // [0,192)
            int type = ri >> 6, d = ri & 63;
            int j = type * 512 + 64 * sl + d;        // GRU row (r/z/n bands)
            const unsigned short* wp = whh_h + (size_t)j * HH;
            float acc = 0.f;
#pragma unroll
            for (int it = 0; it < 8; it++) {
                int k0 = it * 64 + sub * 4;
                ushort4 wv = *(const ushort4*)(wp + k0);
                float4 hv = *(const float4*)&sh_h[k0];
                acc += bf2f(wv.x) * hv.x + bf2f(wv.y) * hv.y
                     + bf2f(wv.z) * hv.z + bf2f(wv.w) * hv.w;
            }
#pragma unroll
            for (int off = 1; off < 16; off <<= 1) acc += __shfl_xor(acc, off);
            ghr[i] = acc;
        }
        bc += NSL; group_bar(ctr, bc);   // Bc: ctx complete

        // ---- P5: pull full ctx
        sh_ctx[tid] = coh_ld(ctxc + (size_t)b * HH + tid);
        sh_ctx[tid + 256] = coh_ld(ctxc + (size_t)b * HH + tid + 256);
        __syncthreads();

        // ---- P6b: W_ih(ctx-half) . ctx dots, combine into gates
        {
            const float* gie_row = gie + ((size_t)(b * SS + s)) * 1536;
#pragma unroll
            for (int i = 0; i < 12; i++) {
                int ri = pair * 12 + i;
                int type = ri >> 6, d = ri & 63;
                int j = type * 512 + 64 * sl + d;
                const unsigned short* wp = wih_h + (size_t)j * HH;
                float acc = 0.f;
#pragma unroll
                for (int it = 0; it < 8; it++) {
                    int k0 = it * 64 + sub * 4;
                    ushort4 wv = *(const ushort4*)(wp + k0);
                    float4 cv = *(const float4*)&sh_ctx[k0];
                    acc += bf2f(wv.x) * cv.x + bf2f(wv.y) * cv.y
                         + bf2f(wv.z) * cv.z + bf2f(wv.w) * cv.w;
                }
#pragma unroll
                for (int off = 1; off < 16; off <<= 1) acc += __shfl_xor(acc, off);
                if (sub == 0) {
                    float gi = acc + gie_row[j];
                    if (type < 2) sh_g[type][d] = gi + ghr[i] + b_hh[j];
                    else { sh_g[2][d] = gi; sh_g[3][d] = ghr[i] + b_hh[j]; }
                }
            }
        }
        __syncthreads();

        // ---- P7: GRU update own-64 dims, push h slice
        if (tid < 64) {
            float r = sigmoid_fast(sh_g[0][tid]);
            float z = sigmoid_fast(sh_g[1][tid]);
            float n = tanh_fast(sh_g[2][tid] + r * sh_g[3][tid]);
            float hn = (1.f - z) * n + z * sh_h[64 * sl + tid];
            hs[((size_t)(b * SS + s)) * HH + 64 * sl + tid] = hn;
            coh_st(hcur + (size_t)b * HH + 64 * sl + tid, hn);
            if (s == SS - 1) out_hT[b * HH + 64 * sl + tid] = hn;
        }
        bc += NSL; group_bar(ctr, bc);   // Bh: h complete

        // ---- pull full h for next step (loop-top syncthreads guards reads)
        sh_h[tid] = coh_ld(hcur + (size_t)b * HH + tid);
        sh_h[tid + 256] = coh_ld(hcur + (size_t)b * HH + tid + 256);
    }
}

// ---------------------------------------------------------------------------
// In-place log_softmax over rows of 32000
__global__ __launch_bounds__(256) void lse_kernel(float* __restrict__ logits) {
    int row = blockIdx.x;
    float* rp = logits + (size_t)row * VV;
    int tid = threadIdx.x;
    __shared__ float red[4];
    __shared__ float bc;
    float m = -INFINITY;
    for (int i = tid; i < VV; i += 256) m = fmaxf(m, rp[i]);
    for (int off = 32; off; off >>= 1) m = fmaxf(m, __shfl_xor(m, off));
    if ((tid & 63) == 0) red[tid >> 6] = m;
    __syncthreads();
    if (tid == 0) bc = fmaxf(fmaxf(red[0], red[1]), fmaxf(red[2], red[3]));
    __syncthreads();
    m = bc;
    float ssum = 0.f;
    for (int i = tid; i < VV; i += 256) ssum += __expf(rp[i] - m);
    for (int off = 32; off; off >>= 1) ssum += __shfl_xor(ssum, off);
    if ((tid & 63) == 0) red[tid >> 6] = ssum;
    __syncthreads();
    if (tid == 0) bc = m + logf(red[0] + red[1] + red[2] + red[3]);
    __syncthreads();
    float lse = bc;
    for (int i = tid; i < VV; i += 256) rp[i] -= lse;
}

// ---------------------------------------------------------------------------
extern "C" void kernel_launch(void* const* d_in, const int* in_sizes, int n_in,
                              void* d_out, int out_size, void* d_ws, size_t ws_size,
                              hipStream_t stream) {
    const float* enc     = (const float*)d_in[0];
    const float* enc_hid = (const float*)d_in[1];
    const int*   tgt     = (const int*)d_in[2];
    const float* emb     = (const float*)d_in[3];
    const float* Wa_w    = (const float*)d_in[4];
    const float* Wa_b    = (const float*)d_in[5];
    const float* Ua_w    = (const float*)d_in[6];
    const float* Ua_b    = (const float*)d_in[7];
    const float* Va_w    = (const float*)d_in[8];
    const float* Va_b    = (const float*)d_in[9];
    const float* W_ih    = (const float*)d_in[10];
    const float* W_hh    = (const float*)d_in[11];
    const float* b_ih    = (const float*)d_in[12];
    const float* b_hh    = (const float*)d_in[13];
    const float* out_w   = (const float*)d_in[14];
    const float* out_b   = (const float*)d_in[15];
    float* out = (float*)d_out;

    float* ws      = (float*)d_ws;
    float* ws_emb  = ws;                          // 2048*512 floats (region0)
    float* ws_ua   = ws_emb + 2048 * 512;         // 2M floats
    float* ws_gie  = ws_ua + 2048 * 1024;         // 2048*1536
    float* ws_hs   = ws_gie + 2048 * 1536;        // 2048*512

    // recur-time aliases inside region0 (emb consumed by then):
    int*   ws_sync = (int*)ws;                    // [0, 2048) ints = 8KB
    float* ws_scp  = ws + 2048;                   // 8*32*128 = 32768
    float* ws_ctxc = ws_scp + NSL * BB * TT;      // 32*512 = 16384
    float* ws_hcur = ws_ctxc + BB * HH;           // 32*512 = 16384
    unsigned short* ws_wah  = (unsigned short*)(ws + 69632);  // 512*512 halfs
    unsigned short* ws_wihh = ws_wah + 512 * 512;             // 1536*512 halfs
    unsigned short* ws_whhh = ws_wihh + 1536 * 512;           // 1536*512 halfs
    // region0 usage ends at float 69632 + 917504/... = 987136 < 1048576  OK

    float* out_logits = out;                                  // [B*S, V]
    float* out_hT     = out + (size_t)BB * SS * VV;           // [B, H]
    float* out_attn   = out_hT + (size_t)BB * HH;             // [B, S, T]

    gather_emb<<<dim3(2048), dim3(256), 0, stream>>>(tgt, emb, ws_emb);
    gemm_bias<<<dim3(8, 64), dim3(256), 0, stream>>>(
        enc, HH, Ua_w, HH, Ua_b, ws_ua, HH, HH);
    gemm_bias<<<dim3(24, 32), dim3(256), 0, stream>>>(
        ws_emb, HH, W_ih, 2 * HH, b_ih, ws_gie, 3 * HH, HH);
    // region0 free now: zero barrier counters, pack bf16 weights
    hipMemsetAsync(d_ws, 0, 8192, stream);
    pack_plain_bf16<<<dim3(1024), dim3(256), 0, stream>>>(Wa_w, ws_wah, 512 * 512);
    pack_wih_bf16<<<dim3(3072), dim3(256), 0, stream>>>(W_ih, ws_wihh);
    pack_plain_bf16<<<dim3(3072), dim3(256), 0, stream>>>(W_hh, ws_whhh, 1536 * 512);
    recur4<<<dim3(BB * NSL), dim3(256), 0, stream>>>(
        enc, enc_hid, ws_wah, Wa_b, Va_w, Va_b, ws_wihh, ws_whhh, b_hh,
        ws_ua, ws_gie, ws_sync, ws_scp, ws_ctxc, ws_hcur, ws_hs, out_hT, out_attn);
    gemm_bias<<<dim3(500, 32), dim3(256), 0, stream>>>(
        ws_hs, HH, out_w, HH, out_b, out_logits, VV, HH);
    lse_kernel<<<dim3(2048), dim3(256), 0, stream>>>(out_logits);
}

// Round 4
// 4552.493 us; speedup vs baseline: 2.2182x; 1.2550x over previous
//
#include <hip/hip_runtime.h>
#include <hip/hip_bf16.h>
#include <math.h>

// Problem constants
#define BB 32     // batch
#define TT 128    // encoder timesteps
#define HH 512    // hidden
#define VV 32000  // vocab
#define SS 64     // decode steps (BLOCK)
#define NSL 8     // slices (blocks) per batch element

__device__ __forceinline__ float tanh_fast(float x) {
    return 1.f - 2.f / (__expf(2.f * x) + 1.f);
}
__device__ __forceinline__ float sigmoid_fast(float x) {
    return 1.f / (1.f + __expf(-x));
}

// Coherent (cross-XCD) accesses — bypass non-coherent L2s, visible at the
// coherence point. Used ONLY for cross-block communicated data.
__device__ __forceinline__ float coh_ld(const float* p) {
    return __hip_atomic_load((const float*)p, __ATOMIC_RELAXED, __HIP_MEMORY_SCOPE_AGENT);
}
__device__ __forceinline__ void coh_st(float* p, float v) {
    __hip_atomic_store(p, v, __ATOMIC_RELAXED, __HIP_MEMORY_SCOPE_AGENT);
}
__device__ __forceinline__ int coh_ldi(const int* p) {
    return __hip_atomic_load((const int*)p, __ATOMIC_RELAXED, __HIP_MEMORY_SCOPE_AGENT);
}
__device__ __forceinline__ void coh_sti(int* p, int v) {
    __hip_atomic_store(p, v, __ATOMIC_RELAXED, __HIP_MEMORY_SCOPE_AGENT);
}
// 8-byte coherent store (two packed floats)
__device__ __forceinline__ void coh_st2(float* p, float x, float y) {
    union { float f[2]; unsigned long long u; } v;
    v.f[0] = x; v.f[1] = y;
    __hip_atomic_store((unsigned long long*)p, v.u,
                       __ATOMIC_RELAXED, __HIP_MEMORY_SCOPE_AGENT);
}

// bf16 helpers (RNE pack, shift-expand)
__device__ __forceinline__ unsigned short f2bf(float f) {
    unsigned int u = __float_as_uint(f);
    u = (u + 0x7fffu + ((u >> 16) & 1u)) >> 16;
    return (unsigned short)u;
}
__device__ __forceinline__ float bf2f(unsigned short h) {
    return __uint_as_float(((unsigned int)h) << 16);
}

// ---------------------------------------------------------------------------
// Gather teacher-forced embeddings
__global__ void gather_emb(const int* __restrict__ tgt,
                           const float* __restrict__ emb,
                           float* __restrict__ out) {
    int r = blockIdx.x;
    int b = r >> 6, s = r & 63;
    int id = (s == 0) ? 1 : tgt[b * SS + (s - 1)];
    const float* ep = emb + (size_t)id * HH;
    float* op = out + (size_t)r * HH;
    op[threadIdx.x] = ep[threadIdx.x];
    op[threadIdx.x + 256] = ep[threadIdx.x + 256];
}

// ---------------------------------------------------------------------------
// Transposed bf16 weight packs (for k-sliced GEMV partials, coalesced reads)
// wa_t[k][o] = Wa_w[o][k]   (512 x 512)
__global__ __launch_bounds__(256) void pack_wa_t(
    const float* __restrict__ src, unsigned short* __restrict__ dst) {
    int i = blockIdx.x * 256 + threadIdx.x;   // 262144
    int k = i >> 9, o = i & 511;
    dst[i] = f2bf(src[(size_t)o * HH + k]);
}
// whh_t[k][j] = W_hh[j][k]  (512 x 1536)
__global__ __launch_bounds__(256) void pack_whh_t(
    const float* __restrict__ src, unsigned short* __restrict__ dst) {
    int i = blockIdx.x * 256 + threadIdx.x;   // 786432
    int k = i / 1536, j = i - k * 1536;
    dst[i] = f2bf(src[(size_t)j * HH + k]);
}

// ---------------------------------------------------------------------------
// Generic fp32 GEMM: C[M,N] = A[M,K] @ B[N,K]^T + bias[N]
__global__ __launch_bounds__(256) void gemm_bias(
    const float* __restrict__ A, int lda,
    const float* __restrict__ Bm, int ldb,
    const float* __restrict__ bias,
    float* __restrict__ C, int ldc, int K) {
    __shared__ float As[16][65];
    __shared__ float Bs[16][65];
    int tid = threadIdx.x;
    int tx = tid & 15, ty = tid >> 4;
    int m0 = blockIdx.y * 64, n0 = blockIdx.x * 64;
    float acc[4][4] = {};
    for (int k0 = 0; k0 < K; k0 += 16) {
#pragma unroll
        for (int i = 0; i < 4; i++) {
            int idx = tid + i * 256;
            int r = idx >> 4, kk = idx & 15;
            As[kk][r] = A[(size_t)(m0 + r) * lda + k0 + kk];
            Bs[kk][r] = Bm[(size_t)(n0 + r) * ldb + k0 + kk];
        }
        __syncthreads();
#pragma unroll
        for (int kk = 0; kk < 16; kk++) {
            float a[4], bv[4];
#pragma unroll
            for (int i = 0; i < 4; i++) a[i] = As[kk][ty * 4 + i];
#pragma unroll
            for (int j = 0; j < 4; j++) bv[j] = Bs[kk][tx * 4 + j];
#pragma unroll
            for (int i = 0; i < 4; i++)
#pragma unroll
                for (int j = 0; j < 4; j++) acc[i][j] += a[i] * bv[j];
        }
        __syncthreads();
    }
#pragma unroll
    for (int i = 0; i < 4; i++) {
        int m = m0 + ty * 4 + i;
#pragma unroll
        for (int j = 0; j < 4; j++) {
            int n = n0 + tx * 4 + j;
            C[(size_t)m * ldc + n] = acc[i][j] + bias[n];
        }
    }
}

// ---------------------------------------------------------------------------
// P_T precompute: P_T[b][t][j] = sum_k enc[b,t,k] * W_ih[j, 512+k], bf16 out.
// Grid (24, 2, 32): per-z GEMM [128 x 512] x [1536 x 512(ld 1024)]^T.
__global__ __launch_bounds__(256) void gemm_pt(
    const float* __restrict__ enc,
    const float* __restrict__ wih_ctx,       // W_ih + 512, ldb = 1024
    unsigned short* __restrict__ P) {
    const float* A = enc + (size_t)blockIdx.z * TT * HH;
    unsigned short* C = P + (size_t)blockIdx.z * TT * 1536;
    __shared__ float As[16][65];
    __shared__ float Bs[16][65];
    int tid = threadIdx.x;
    int tx = tid & 15, ty = tid >> 4;
    int m0 = blockIdx.y * 64, n0 = blockIdx.x * 64;
    float acc[4][4] = {};
    for (int k0 = 0; k0 < HH; k0 += 16) {
#pragma unroll
        for (int i = 0; i < 4; i++) {
            int idx = tid + i * 256;
            int r = idx >> 4, kk = idx & 15;
            As[kk][r] = A[(size_t)(m0 + r) * HH + k0 + kk];
            Bs[kk][r] = wih_ctx[(size_t)(n0 + r) * 1024 + k0 + kk];
        }
        __syncthreads();
#pragma unroll
        for (int kk = 0; kk < 16; kk++) {
            float a[4], bv[4];
#pragma unroll
            for (int i = 0; i < 4; i++) a[i] = As[kk][ty * 4 + i];
#pragma unroll
            for (int j = 0; j < 4; j++) bv[j] = Bs[kk][tx * 4 + j];
#pragma unroll
            for (int i = 0; i < 4; i++)
#pragma unroll
                for (int j = 0; j < 4; j++) acc[i][j] += a[i] * bv[j];
        }
        __syncthreads();
    }
#pragma unroll
    for (int i = 0; i < 4; i++) {
        int m = m0 + ty * 4 + i;
#pragma unroll
        for (int j = 0; j < 4; j++) {
            int n = n0 + tx * 4 + j;
            C[(size_t)m * 1536 + n] = f2bf(acc[i][j]);
        }
    }
}

// ---------------------------------------------------------------------------
// RMW-free group barrier: per-block stamp slots (64B-padded), monotonic stamp.
// Arrival = plain coherent store after per-wave vmcnt drain + __syncthreads.
// Wait = every thread polls all 8 slots with one unrolled 8-wide load burst.
__device__ __forceinline__ void slot_bar(int* sb, int sl, int stamp) {
    asm volatile("s_waitcnt vmcnt(0)" ::: "memory");
    __syncthreads();
    if (threadIdx.x == 0) coh_sti(sb + sl * 16, stamp);
    for (;;) {
        int v0 = coh_ldi(sb + 0),   v1 = coh_ldi(sb + 16);
        int v2 = coh_ldi(sb + 32),  v3 = coh_ldi(sb + 48);
        int v4 = coh_ldi(sb + 64),  v5 = coh_ldi(sb + 80);
        int v6 = coh_ldi(sb + 96),  v7 = coh_ldi(sb + 112);
        int m = min(min(min(v0, v1), min(v2, v3)), min(min(v4, v5), min(v6, v7)));
        if (m >= stamp) break;
        __builtin_amdgcn_s_sleep(1);
    }
    asm volatile("" ::: "memory");
}

// ---------------------------------------------------------------------------
// Distributed recurrence v5: 256 blocks = 32 batch x 8 slices, 256 threads.
// Only TWO barriers per step:
//   Phase A (local, from own h slice): k-sliced q partials (all 512 o) and
//            k-sliced W_hh.h partials (all 1536 j).      -> B1
//   Phase B: pull own q + own ghh sums; score partials.  -> B2
//   Phase C: softmax; gate ctx-part via precomputed P_T (W_ih_ctx.enc^T),
//            GRU update — all local. Full h / ctx never materialized.
__global__ __launch_bounds__(256) void recur5(
    const float* __restrict__ enc_hid,          // [1,B,H]
    const unsigned short* __restrict__ wa_t,    // [512 k][512 o] bf16
    const float* __restrict__ Wa_b,
    const float* __restrict__ Va_w, const float* __restrict__ Va_b,
    const unsigned short* __restrict__ whh_t,   // [512 k][1536 j] bf16
    const float* __restrict__ b_hh,
    const float* __restrict__ ua,               // [B,T,H] fp32
    const float* __restrict__ gie,              // [B*S, 3H] (includes b_ih)
    const unsigned short* __restrict__ pt,      // [B][T][1536] bf16
    int* __restrict__ slots,                    // [B][8] stamps, 64B padded
    float* __restrict__ qpp,                    // [B][8][512]
    float* __restrict__ ghhp,                   // [B][8][1536]
    float* __restrict__ scp,                    // [B][8][128]
    float* __restrict__ hs,                     // [B*S, H]
    float* __restrict__ out_hT,                 // [B,H]
    float* __restrict__ out_attn) {             // [B,S,T]
    int blk = blockIdx.x;
    int b = blk >> 3, sl = blk & 7;
    int tid = threadIdx.x;
    int w = tid >> 6, lane = tid & 63;

    __shared__ __align__(16) float sh_h[64];
    __shared__ __align__(16) float sh_q[64];
    __shared__ float sh_sc[TT], sh_w[TT];
    __shared__ float sh_ghh[3][64];
    __shared__ float sh_gc[3][64];

    int* sb = slots + b * 128;
    float* qp_my  = qpp  + (size_t)(b * NSL + sl) * 512;
    float* ghh_my = ghhp + (size_t)(b * NSL + sl) * 1536;
    float* scp_my = scp  + (size_t)(b * NSL + sl) * TT;

    if (tid < 64) sh_h[tid] = enc_hid[b * HH + 64 * sl + tid];

    for (int s = 0; s < SS; s++) {
        __syncthreads();   // sh_h ready (init or previous Phase C)

        // ---- Phase A: k-sliced partials from own h (coalesced, no shuffles)
        {
            const unsigned short* wp = wa_t  + (size_t)(64 * sl) * 512  + 2 * tid;
            const unsigned short* hp = whh_t + (size_t)(64 * sl) * 1536 + 2 * tid;
            float a0 = 0.f, a1 = 0.f;
            float g0 = 0.f, g1 = 0.f, g2 = 0.f, g3 = 0.f, g4 = 0.f, g5 = 0.f;
#pragma unroll 4
            for (int kk = 0; kk < 64; kk++) {
                float hk = sh_h[kk];
                unsigned int uq = *(const unsigned int*)(wp + (size_t)kk * 512);
                unsigned int u0 = *(const unsigned int*)(hp + (size_t)kk * 1536);
                unsigned int u1 = *(const unsigned int*)(hp + (size_t)kk * 1536 + 512);
                unsigned int u2 = *(const unsigned int*)(hp + (size_t)kk * 1536 + 1024);
                a0 += bf2f((unsigned short)uq) * hk;
                a1 += bf2f((unsigned short)(uq >> 16)) * hk;
                g0 += bf2f((unsigned short)u0) * hk;
                g1 += bf2f((unsigned short)(u0 >> 16)) * hk;
                g2 += bf2f((unsigned short)u1) * hk;
                g3 += bf2f((unsigned short)(u1 >> 16)) * hk;
                g4 += bf2f((unsigned short)u2) * hk;
                g5 += bf2f((unsigned short)(u2 >> 16)) * hk;
            }
            coh_st2(qp_my + 2 * tid, a0, a1);
            coh_st2(ghh_my + 2 * tid, g0, g1);
            coh_st2(ghh_my + 512 + 2 * tid, g2, g3);
            coh_st2(ghh_my + 1024 + 2 * tid, g4, g5);
        }
        slot_bar(sb, sl, 2 * s + 1);   // B1: q/ghh partials complete

        // ---- Phase B: pull own sums; compute score partials
        if (tid < 64) {
            int o = 64 * sl + tid;
            float q = Wa_b[o];
#pragma unroll
            for (int p2 = 0; p2 < NSL; p2++)
                q += coh_ld(qpp + (size_t)(b * NSL + p2) * 512 + o);
            sh_q[tid] = q;
        }
        if (tid < 192) {
            int c = tid >> 6, d = tid & 63;
            int j = c * 512 + 64 * sl + d;
            float g = b_hh[j];
#pragma unroll
            for (int p2 = 0; p2 < NSL; p2++)
                g += coh_ld(ghhp + (size_t)(b * NSL + p2) * 1536 + j);
            sh_ghh[c][d] = g;
        }
        __syncthreads();
        {
            float va = Va_w[64 * sl + lane];
            float myq = sh_q[lane];
            const float* uab = ua + ((size_t)b * TT + w * 32) * HH + 64 * sl + lane;
#pragma unroll 4
            for (int t2 = 0; t2 < 32; t2++) {
                float x = tanh_fast(myq + uab[(size_t)t2 * HH]) * va;
#pragma unroll
                for (int off = 32; off; off >>= 1) x += __shfl_xor(x, off);
                if (lane == 0) coh_st(scp_my + w * 32 + t2, x);
            }
        }
        slot_bar(sb, sl, 2 * s + 2);   // B2: score partials complete

        // ---- Phase C: softmax (redundant), gates via P_T, GRU — all local
        if (tid < TT) {
            float sc = Va_b[0];
#pragma unroll
            for (int p2 = 0; p2 < NSL; p2++)
                sc += coh_ld(scp + (size_t)(b * NSL + p2) * TT + tid);
            sh_sc[tid] = sc;
        }
        __syncthreads();
        if (tid < 64) {
            float a = sh_sc[tid], c = sh_sc[tid + 64];
            float m = fmaxf(a, c);
            for (int off = 32; off; off >>= 1) m = fmaxf(m, __shfl_xor(m, off));
            float ea = __expf(a - m), ec = __expf(c - m);
            float ssum = ea + ec;
            for (int off = 32; off; off >>= 1) ssum += __shfl_xor(ssum, off);
            float inv = 1.f / ssum;
            sh_w[tid] = ea * inv;
            sh_w[tid + 64] = ec * inv;
            if (sl == 0) {
                float* ap = out_attn + ((size_t)(b * SS + s)) * TT;
                ap[tid] = ea * inv;
                ap[tid + 64] = ec * inv;
            }
        }
        __syncthreads();
        // gate ctx-part: gc[j] = sum_t w[t] * P_T[b][t][j]  (own 192 rows)
        if (tid < 192) {
            int c = tid >> 6, d = tid & 63;
            int j = c * 512 + 64 * sl + d;
            const unsigned short* pb = pt + (size_t)b * TT * 1536 + j;
            float acc = 0.f;
#pragma unroll 8
            for (int t2 = 0; t2 < TT; t2++)
                acc += sh_w[t2] * bf2f(pb[(size_t)t2 * 1536]);
            sh_gc[c][d] = acc + gie[((size_t)(b * SS + s)) * 1536 + j];
        }
        __syncthreads();
        if (tid < 64) {
            float r = sigmoid_fast(sh_gc[0][tid] + sh_ghh[0][tid]);
            float z = sigmoid_fast(sh_gc[1][tid] + sh_ghh[1][tid]);
            float n = tanh_fast(sh_gc[2][tid] + r * sh_ghh[2][tid]);
            float hn = (1.f - z) * n + z * sh_h[tid];
            sh_h[tid] = hn;
            hs[((size_t)(b * SS + s)) * HH + 64 * sl + tid] = hn;
            if (s == SS - 1) out_hT[b * HH + 64 * sl + tid] = hn;
        }
    }
}

// ---------------------------------------------------------------------------
// In-place log_softmax over rows of 32000
__global__ __launch_bounds__(256) void lse_kernel(float* __restrict__ logits) {
    int row = blockIdx.x;
    float* rp = logits + (size_t)row * VV;
    int tid = threadIdx.x;
    __shared__ float red[4];
    __shared__ float bc;
    float m = -INFINITY;
    for (int i = tid; i < VV; i += 256) m = fmaxf(m, rp[i]);
    for (int off = 32; off; off >>= 1) m = fmaxf(m, __shfl_xor(m, off));
    if ((tid & 63) == 0) red[tid >> 6] = m;
    __syncthreads();
    if (tid == 0) bc = fmaxf(fmaxf(red[0], red[1]), fmaxf(red[2], red[3]));
    __syncthreads();
    m = bc;
    float ssum = 0.f;
    for (int i = tid; i < VV; i += 256) ssum += __expf(rp[i] - m);
    for (int off = 32; off; off >>= 1) ssum += __shfl_xor(ssum, off);
    if ((tid & 63) == 0) red[tid >> 6] = ssum;
    __syncthreads();
    if (tid == 0) bc = m + logf(red[0] + red[1] + red[2] + red[3]);
    __syncthreads();
    float lse = bc;
    for (int i = tid; i < VV; i += 256) rp[i] -= lse;
}

// ---------------------------------------------------------------------------
extern "C" void kernel_launch(void* const* d_in, const int* in_sizes, int n_in,
                              void* d_out, int out_size, void* d_ws, size_t ws_size,
                              hipStream_t stream) {
    const float* enc     = (const float*)d_in[0];
    const float* enc_hid = (const float*)d_in[1];
    const int*   tgt     = (const int*)d_in[2];
    const float* emb     = (const float*)d_in[3];
    const float* Wa_w    = (const float*)d_in[4];
    const float* Wa_b    = (const float*)d_in[5];
    const float* Ua_w    = (const float*)d_in[6];
    const float* Ua_b    = (const float*)d_in[7];
    const float* Va_w    = (const float*)d_in[8];
    const float* Va_b    = (const float*)d_in[9];
    const float* W_ih    = (const float*)d_in[10];
    const float* W_hh    = (const float*)d_in[11];
    const float* b_ih    = (const float*)d_in[12];
    const float* b_hh    = (const float*)d_in[13];
    const float* out_w   = (const float*)d_in[14];
    const float* out_b   = (const float*)d_in[15];
    float* out = (float*)d_out;

    float* ws      = (float*)d_ws;
    float* ws_emb  = ws;                          // [0, 1048576) floats
    float* ws_ua   = ws + 1048576;                // 2M floats
    float* ws_gie  = ws_ua + 2097152;             // 3,145,728 floats
    float* ws_hs   = ws_gie + 3145728;            // 1,048,576 floats
    // recur-time aliases inside region0 (emb consumed by then):
    int*   ws_slots = (int*)ws;                   // 32 groups x 8 slots x 64B
    float* ws_qpp   = ws + 4096;                  // [32][8][512]  = 131072
    float* ws_ghhp  = ws_qpp + BB * NSL * 512;    // [32][8][1536] = 393216
    float* ws_scp   = ws_ghhp + BB * NSL * 1536;  // [32][8][128]  = 32768
    // region0 high-water: 4096+131072+393216+32768 = 561152 < 1048576  OK

    float* out_logits = out;                                  // [B*S, V]
    float* out_hT     = out + (size_t)BB * SS * VV;           // [B, H]
    float* out_attn   = out_hT + (size_t)BB * HH;             // [B, S, T]

    // Dead-until-final-GEMM scratch inside out_logits (65.5M floats):
    unsigned short* s_pt  = (unsigned short*)out;             // 6,291,456 u
    unsigned short* s_wat = (unsigned short*)(out + 3200000); //   262,144 u
    unsigned short* s_wht = (unsigned short*)(out + 3400000); //   786,432 u
    // scratch high-water: float 3,793,216 << 65,536,000 — fully overwritten
    // by the final logits GEMM afterwards.

    gather_emb<<<dim3(2048), dim3(256), 0, stream>>>(tgt, emb, ws_emb);
    gemm_bias<<<dim3(8, 64), dim3(256), 0, stream>>>(
        enc, HH, Ua_w, HH, Ua_b, ws_ua, HH, HH);
    gemm_bias<<<dim3(24, 32), dim3(256), 0, stream>>>(
        ws_emb, HH, W_ih, 2 * HH, b_ih, ws_gie, 3 * HH, HH);
    // region0 free now: zero barrier slots; build packs + P_T
    hipMemsetAsync(d_ws, 0, 16384, stream);
    pack_wa_t<<<dim3(1024), dim3(256), 0, stream>>>(Wa_w, s_wat);
    pack_whh_t<<<dim3(3072), dim3(256), 0, stream>>>(W_hh, s_wht);
    gemm_pt<<<dim3(24, 2, 32), dim3(256), 0, stream>>>(enc, W_ih + 512, s_pt);
    recur5<<<dim3(BB * NSL), dim3(256), 0, stream>>>(
        enc_hid, s_wat, Wa_b, Va_w, Va_b, s_wht, b_hh,
        ws_ua, ws_gie, s_pt, ws_slots, ws_qpp, ws_ghhp, ws_scp,
        ws_hs, out_hT, out_attn);
    gemm_bias<<<dim3(500, 32), dim3(256), 0, stream>>>(
        ws_hs, HH, out_w, HH, out_b, out_logits, VV, HH);
    lse_kernel<<<dim3(2048), dim3(256), 0, stream>>>(out_logits);
}